// Round 5
// baseline (198.861 us; speedup 1.0000x reference)
//
#include <hip/hip_runtime.h>
#include <hip/hip_bf16.h>

typedef __attribute__((ext_vector_type(8))) short bf16x8;
typedef __attribute__((ext_vector_type(4))) float f32x4;

#define LDS_STRIDE 528   // bytes per LDS row (132 dwords; %32 banks = 4, 16B-aligned)

// ---------------- helpers ----------------
__device__ __forceinline__ float waveSum(float v) {
    for (int d = 32; d; d >>= 1) v += __shfl_xor(v, d, 64);
    return v;
}
__device__ __forceinline__ unsigned short f2bf(float f) {
    union { float f; unsigned int u; } v; v.f = f;
    unsigned int r = (v.u + 0x7FFF + ((v.u >> 16) & 1)) >> 16;
    return (unsigned short)r;
}
__device__ __forceinline__ float bf2f(unsigned int hbits) {
    union { unsigned int u; float f; } v; v.u = hbits << 16;
    return v.f;
}

// ---------------- setup: zero counts | pack [W|W_res] to B-frag order | rel_logit ----------------
__global__ __launch_bounds__(256) void setup_kernel(
    int* __restrict__ counts, int N,
    const float* __restrict__ W, const float* __restrict__ W_res,
    unsigned short* __restrict__ WbPack,
    const float* __restrict__ W_r, const float* __restrict__ a,
    const float* __restrict__ rel_emb, float* __restrict__ rl,
    int n_rel, int rel_dim, int zb)
{
    __shared__ float a3[128];
    __shared__ float wa[128];
    int bid = blockIdx.x;
    int tid = threadIdx.x;
    if (bid < zb) {
        int i = bid * 256 + tid;
        if (i < N) counts[i] = 0;
        return;
    }
    if (bid < zb + 16) {
        int g = (bid - zb) * 256 + tid;   // 0..4095
        int t = g >> 8;
        int s = (g >> 6) & 3;
        int lane = g & 63;
        int ncol = ((t & 7) << 4) + (lane & 15);
        int k0 = s * 32 + ((lane >> 4) << 3);
        const float* srcw = (t < 8) ? W : W_res;
        unsigned short* dst = WbPack + ((size_t)(t * 4 + s) * 64 + lane) * 8;
        #pragma unroll
        for (int j = 0; j < 8; ++j) dst[j] = f2bf(srcw[(size_t)(k0 + j) * 128 + ncol]);
        return;
    }
    // rel_logit block
    if (tid < 128) {
        a3[tid] = a[256 + tid];
    }
    __syncthreads();
    if (tid < rel_dim) {
        float s = 0.f;
        for (int d = 0; d < 128; ++d) s += W_r[tid * 128 + d] * a3[d];
        wa[tid] = s;
    }
    __syncthreads();
    if (tid < n_rel) {
        float s = 0.f;
        for (int k = 0; k < rel_dim; ++k) s += rel_emb[tid * rel_dim + k] * wa[k];
        rl[tid] = s;
    }
}

// ---------------- dual GEMM via MFMA: [hb | resb] = bf16( X @ [W | W_res] ) + fused p/q ----------------
__global__ __launch_bounds__(256) void gemm_dual_kernel(
    const float* __restrict__ X, const unsigned short* __restrict__ WbPack,
    const float* __restrict__ b_res, const float* __restrict__ a,
    unsigned short* __restrict__ hb, unsigned short* __restrict__ resb,
    float* __restrict__ p, float* __restrict__ q, int M)
{
    __shared__ __align__(16) unsigned char smem[64 * LDS_STRIDE];
    __shared__ float pq_s[128];
    const int tid = threadIdx.x;
    const int lane = tid & 63;
    const int wave = tid >> 6;
    const int rowbase = blockIdx.x * 64;
    const int c16 = lane & 15;
    const int kq = lane >> 4;    // 0..3

    if (tid < 128) pq_s[tid] = 0.f;

    // hoist this wave's 16 W fragments (t = wave*4+tt, s = 0..3)
    bf16x8 wfrag[4][4];
    #pragma unroll
    for (int tt = 0; tt < 4; ++tt)
        #pragma unroll
        for (int s = 0; s < 4; ++s)
            wfrag[tt][s] = *(const bf16x8*)(WbPack + ((size_t)((wave * 4 + tt) * 4 + s) * 64 + lane) * 8);

    float bres[4];
    #pragma unroll
    for (int tt = 0; tt < 4; ++tt) {
        int t = wave * 4 + tt;
        bres[tt] = (t >= 8) ? b_res[(t - 8) * 16 + c16] : 0.f;
    }
    float pa[4], qa[4];
    #pragma unroll
    for (int tt = 0; tt < 4; ++tt) {
        int col = (wave * 4 + tt) * 16 + c16;
        pa[tt] = (wave < 2) ? a[col] : 0.f;
        qa[tt] = (wave < 2) ? a[128 + col] : 0.f;
    }

    // stage X tile (64 rows x 128 f32) -> LDS bf16
    #pragma unroll
    for (int j = 0; j < 8; ++j) {
        int ch = j * 256 + tid;            // 16B chunk id, 0..2047
        int r = ch >> 5;
        int c = ch & 31;
        int gr = rowbase + r; if (gr >= M) gr = M - 1;
        float4 v = *(const float4*)(X + (size_t)gr * 128 + c * 4);
        unsigned int u0 = ((unsigned)f2bf(v.y) << 16) | f2bf(v.x);
        unsigned int u1 = ((unsigned)f2bf(v.w) << 16) | f2bf(v.z);
        *(uint2*)(smem + r * LDS_STRIDE + c * 8) = make_uint2(u0, u1);
    }
    __syncthreads();

    f32x4 acc[4][4];
    #pragma unroll
    for (int rt = 0; rt < 4; ++rt)
        #pragma unroll
        for (int tt = 0; tt < 4; ++tt) acc[rt][tt] = (f32x4){0.f, 0.f, 0.f, 0.f};

    #pragma unroll
    for (int s = 0; s < 4; ++s) {
        #pragma unroll
        for (int rt = 0; rt < 4; ++rt) {
            int row = rt * 16 + c16;
            bf16x8 af = *(const bf16x8*)(smem + row * LDS_STRIDE + s * 64 + kq * 16);
            #pragma unroll
            for (int tt = 0; tt < 4; ++tt)
                acc[rt][tt] = __builtin_amdgcn_mfma_f32_16x16x32_bf16(af, wfrag[tt][s], acc[rt][tt], 0, 0, 0);
        }
    }
    __syncthreads();

    if (wave < 2) {
        #pragma unroll
        for (int rt = 0; rt < 4; ++rt) {
            #pragma unroll
            for (int i = 0; i < 4; ++i) {
                float pp = 0.f, qq = 0.f;
                #pragma unroll
                for (int tt = 0; tt < 4; ++tt) {
                    pp += acc[rt][tt][i] * pa[tt];
                    qq += acc[rt][tt][i] * qa[tt];
                }
                #pragma unroll
                for (int d = 1; d < 16; d <<= 1) {
                    pp += __shfl_xor(pp, d, 64);
                    qq += __shfl_xor(qq, d, 64);
                }
                if (c16 == 0) {
                    int r = rt * 16 + kq * 4 + i;
                    atomicAdd(&pq_s[r], pp);
                    atomicAdd(&pq_s[64 + r], qq);
                }
            }
        }
    }

    #pragma unroll
    for (int rt = 0; rt < 4; ++rt) {
        #pragma unroll
        for (int tt = 0; tt < 4; ++tt) {
            int colall = (wave * 4 + tt) * 16 + c16;
            #pragma unroll
            for (int i = 0; i < 4; ++i) {
                int row = rt * 16 + kq * 4 + i;
                *(unsigned short*)(smem + row * LDS_STRIDE + colall * 2) = f2bf(acc[rt][tt][i] + bres[tt]);
            }
        }
    }
    __syncthreads();

    #pragma unroll
    for (int j = 0; j < 4; ++j) {
        int ch = j * 256 + tid;
        int r = ch >> 4;
        int c = ch & 15;
        int gr = rowbase + r;
        uint4 hv = *(const uint4*)(smem + r * LDS_STRIDE + c * 16);
        uint4 rv = *(const uint4*)(smem + r * LDS_STRIDE + 256 + c * 16);
        if (gr < M) {
            *(uint4*)(hb + (size_t)gr * 128 + c * 8) = hv;
            *(uint4*)(resb + (size_t)gr * 128 + c * 8) = rv;
        }
    }
    if (tid < 64) {
        int gr = rowbase + tid;
        if (gr < M) { p[gr] = pq_s[tid]; q[gr] = pq_s[64 + tid]; }
    }
}

// ---------------- fused: logit -> exp (edge-order pack), histogram with rank capture ----------------
__global__ __launch_bounds__(256) void edge_kernel(
    const int* __restrict__ src, const int* __restrict__ dst, const int* __restrict__ etype,
    const float* __restrict__ p, const float* __restrict__ q, const float* __restrict__ rl,
    int* __restrict__ counts, int* __restrict__ rank, uint2* __restrict__ pair0,
    int E, int n_rel)
{
    __shared__ float rls[64];
    if (threadIdx.x < n_rel) rls[threadIdx.x] = rl[threadIdx.x];
    __syncthreads();
    int e = blockIdx.x * 256 + threadIdx.x;
    if (e >= E) return;
    int s = src[e], d = dst[e], t = etype[e];
    float l = p[d] + q[s] + rls[t];
    l = (l > 0.f) ? l : 0.2f * l;
    float ex = __expf(l);   // softmax shift-invariant; logits O(+-10), no overflow
    uint2 pk;
    pk.x = (unsigned int)s;
    pk.y = __float_as_uint(ex);
    pair0[e] = pk;
    rank[e] = atomicAdd(&counts[d], 1);
}

__global__ __launch_bounds__(1024) void scan_block(const int* __restrict__ counts, int* __restrict__ tmp,
                                                   int* __restrict__ bsums, int n)
{
    __shared__ int wsum[16];
    int tid = threadIdx.x;
    int i = blockIdx.x * 1024 + tid;
    int v = (i < n) ? counts[i] : 0;
    int lane = tid & 63, w = tid >> 6;
    int x = v;
    #pragma unroll
    for (int d = 1; d < 64; d <<= 1) { int t = __shfl_up(x, d, 64); if (lane >= d) x += t; }
    if (lane == 63) wsum[w] = x;
    __syncthreads();
    if (w == 0) {
        int s = (lane < 16) ? wsum[lane] : 0;
        #pragma unroll
        for (int d = 1; d < 16; d <<= 1) { int t = __shfl_up(s, d, 64); if (lane >= d) s += t; }
        if (lane < 16) wsum[lane] = s;
    }
    __syncthreads();
    if (w > 0) x += wsum[w - 1];
    if (i < n) tmp[i] = x;
    if (tid == 1023) bsums[blockIdx.x] = x;
}

__global__ void scan_partials(const int* __restrict__ bsums, int* __restrict__ bpref, int nb)
{
    int lane = threadIdx.x; // 64
    int v = (lane < nb) ? bsums[lane] : 0;
    int x = v;
    #pragma unroll
    for (int d = 1; d < 64; d <<= 1) { int t = __shfl_up(x, d, 64); if (lane >= d) x += t; }
    if (lane < nb) bpref[lane] = x - v; // exclusive
}

__global__ __launch_bounds__(1024) void finalize_offsets(const int* __restrict__ tmp, const int* __restrict__ counts,
                                                         const int* __restrict__ bpref, int* __restrict__ offsets,
                                                         int N, int E)
{
    int i = blockIdx.x * 1024 + threadIdx.x;
    if (i < N) offsets[i] = tmp[i] - counts[i] + bpref[blockIdx.x];
    if (i == 0) offsets[N] = E;
}

// ---------------- permute index: perm[offsets[d] + rank[e]] = e  (4B random store) ----------------
__global__ __launch_bounds__(256) void scatter_kernel(
    const int* __restrict__ dst, const int* __restrict__ rank,
    const int* __restrict__ offsets, int* __restrict__ perm, int E)
{
    int e = blockIdx.x * 256 + threadIdx.x;
    if (e >= E) return;
    int d = dst[e];
    int pos = offsets[d] + rank[e];
    perm[pos] = e;
}

// ---------------- per-node normalize + aggregate + residual + SELU (1 wave / node) ----------------
// 32 lanes per edge-row (uint2 = 4 bf16 per lane); 2 edges per wave-iteration, unroll x2.
__global__ __launch_bounds__(256) void agg_kernel(
    const unsigned short* __restrict__ hb, const unsigned short* __restrict__ resb,
    const int* __restrict__ offsets, const int* __restrict__ perm, const uint2* __restrict__ pair0,
    float* __restrict__ out, int N)
{
    int node = blockIdx.x * 4 + (threadIdx.x >> 6);
    int lane = threadIdx.x & 63;
    if (node >= N) return;
    int beg = offsets[node], end = offsets[node + 1];

    const int half = lane >> 5;    // which of 2 concurrent edges
    const int sub = lane & 31;     // col group: bf16 cols sub*4 .. +3
    float ac0 = 0.f, ac1 = 0.f, ac2 = 0.f, ac3 = 0.f;
    float ssum = 0.f;
    const unsigned short* hsub = hb + sub * 4;

    for (int c = beg; c < end; c += 64) {
        int nn = min(64, end - c);
        uint2 pk = make_uint2(0u, 0u);
        if (lane < nn) {
            int e = perm[c + lane];
            pk = pair0[e];
        }
        int   sv = (int)pk.x;
        float se = __uint_as_float(pk.y);
        ssum += se;   // out-of-range lanes contribute 0

        int j = 0;
        for (; j + 3 < nn; j += 4) {
            int j0 = j + half, j1 = j + 2 + half;
            float w0 = __shfl(se, j0), w1 = __shfl(se, j1);
            int   r0 = __shfl(sv, j0), r1 = __shfl(sv, j1);
            uint2 h0 = *(const uint2*)(hsub + (size_t)r0 * 128);
            uint2 h1 = *(const uint2*)(hsub + (size_t)r1 * 128);
            ac0 += w0 * bf2f(h0.x & 0xffff); ac1 += w0 * bf2f(h0.x >> 16);
            ac2 += w0 * bf2f(h0.y & 0xffff); ac3 += w0 * bf2f(h0.y >> 16);
            ac0 += w1 * bf2f(h1.x & 0xffff); ac1 += w1 * bf2f(h1.x >> 16);
            ac2 += w1 * bf2f(h1.y & 0xffff); ac3 += w1 * bf2f(h1.y >> 16);
        }
        for (; j < nn; j += 2) {
            int jj = j + half;
            bool ok = (jj < nn);
            float w = ok ? __shfl(se, jj) : 0.f;
            int   r = __shfl(sv, ok ? jj : j);
            uint2 hv = *(const uint2*)(hsub + (size_t)r * 128);
            ac0 += w * bf2f(hv.x & 0xffff); ac1 += w * bf2f(hv.x >> 16);
            ac2 += w * bf2f(hv.y & 0xffff); ac3 += w * bf2f(hv.y >> 16);
        }
    }

    // combine the two edge-halves; reduce ssum across wave
    ac0 += __shfl_xor(ac0, 32, 64);
    ac1 += __shfl_xor(ac1, 32, 64);
    ac2 += __shfl_xor(ac2, 32, 64);
    ac3 += __shfl_xor(ac3, 32, 64);
    ssum = waveSum(ssum);
    float inv = 1.0f / (ssum + 1e-16f);

    if (half == 0) {
        uint2 rv = *(const uint2*)(resb + (size_t)node * 128 + sub * 4);
        float o0 = ac0 * inv + bf2f(rv.x & 0xffff);
        float o1 = ac1 * inv + bf2f(rv.x >> 16);
        float o2 = ac2 * inv + bf2f(rv.y & 0xffff);
        float o3 = ac3 * inv + bf2f(rv.y >> 16);
        const float SC = 1.0507009873554805f, AL = 1.6732632423543772f;
        o0 = (o0 > 0.f) ? SC * o0 : SC * AL * (__expf(o0) - 1.f);
        o1 = (o1 > 0.f) ? SC * o1 : SC * AL * (__expf(o1) - 1.f);
        o2 = (o2 > 0.f) ? SC * o2 : SC * AL * (__expf(o2) - 1.f);
        o3 = (o3 > 0.f) ? SC * o3 : SC * AL * (__expf(o3) - 1.f);
        *(float4*)(out + (size_t)node * 128 + sub * 4) = make_float4(o0, o1, o2, o3);
    }
}

// ---------------- launch ----------------
extern "C" void kernel_launch(void* const* d_in, const int* in_sizes, int n_in,
                              void* d_out, int out_size, void* d_ws, size_t ws_size,
                              hipStream_t stream)
{
    const float* X      = (const float*)d_in[0];
    const int*   ei     = (const int*)d_in[1];
    const int*   etype  = (const int*)d_in[2];
    const float* W      = (const float*)d_in[3];
    const float* W_r    = (const float*)d_in[4];
    const float* a      = (const float*)d_in[5];
    const float* W_res  = (const float*)d_in[6];
    const float* b_res  = (const float*)d_in[7];
    const float* rel_emb= (const float*)d_in[8];

    const int N = in_sizes[0] / 128;     // 50000
    const int E = in_sizes[2];           // 600000
    const int n_rel = in_sizes[8] / 100; // 40
    const int* src = ei;
    const int* dst = ei + E;

    // workspace carve (256B aligned)
    char* w = (char*)d_ws;
    auto alloc = [&](size_t bytes) -> void* {
        void* ptr = (void*)w;
        w += (bytes + 255) & ~(size_t)255;
        return ptr;
    };
    unsigned short* WbPack = (unsigned short*)alloc((size_t)16 * 4 * 64 * 8 * 2);
    unsigned short* hb     = (unsigned short*)alloc((size_t)N * 128 * 2);
    unsigned short* resb   = (unsigned short*)alloc((size_t)N * 128 * 2);
    float* p       = (float*)alloc((size_t)N * 4);
    float* q       = (float*)alloc((size_t)N * 4);
    float* rl      = (float*)alloc(64 * 4);
    int*   counts  = (int*)alloc((size_t)N * 4);
    int*   tmp     = (int*)alloc((size_t)(N + 2) * 4);
    int*   offsets = (int*)alloc((size_t)(N + 2) * 4);
    int*   bsums   = (int*)alloc(256 * 4);
    int*   bpref   = (int*)alloc(256 * 4);
    int*   rank    = (int*)alloc((size_t)E * 4);
    uint2* pair0   = (uint2*)alloc((size_t)E * 8);
    int*   perm    = (int*)alloc((size_t)E * 4);
    float* out     = (float*)d_out;

    const int zb = (N + 255) / 256;                 // 196
    const int gemm_blocks = (N + 63) / 64;          // 782
    const int node_wave_blocks = (N + 3) / 4;       // 12500
    const int edge_blocks = (E + 255) / 256;        // 2344
    const int scan_blocks = (N + 1023) / 1024;      // 49

    setup_kernel<<<zb + 17, 256, 0, stream>>>(counts, N, W, W_res, WbPack,
                                              W_r, a, rel_emb, rl, n_rel, 100, zb);
    gemm_dual_kernel<<<gemm_blocks, 256, 0, stream>>>(X, WbPack, b_res, a, hb, resb, p, q, N);

    edge_kernel<<<edge_blocks, 256, 0, stream>>>(src, dst, etype, p, q, rl,
                                                 counts, rank, pair0, E, n_rel);
    scan_block<<<scan_blocks, 1024, 0, stream>>>(counts, tmp, bsums, N);
    scan_partials<<<1, 64, 0, stream>>>(bsums, bpref, scan_blocks);
    finalize_offsets<<<scan_blocks, 1024, 0, stream>>>(tmp, counts, bpref, offsets, N, E);

    scatter_kernel<<<edge_blocks, 256, 0, stream>>>(dst, rank, offsets, perm, E);
    agg_kernel<<<node_wave_blocks, 256, 0, stream>>>(hb, resb, offsets, perm, pair0, out, N);
}

// Round 6
// 192.900 us; speedup vs baseline: 1.0309x; 1.0309x over previous
//
#include <hip/hip_runtime.h>
#include <hip/hip_bf16.h>

typedef __attribute__((ext_vector_type(8))) short bf16x8;
typedef __attribute__((ext_vector_type(4))) float f32x4;

#define LDS_STRIDE 528   // bytes per LDS row (132 dwords; %32 banks = 4, 16B-aligned)

// ---------------- helpers ----------------
__device__ __forceinline__ float waveSum(float v) {
    for (int d = 32; d; d >>= 1) v += __shfl_xor(v, d, 64);
    return v;
}
__device__ __forceinline__ int waveSumI(int v) {
    for (int d = 32; d; d >>= 1) v += __shfl_xor(v, d, 64);
    return v;
}
__device__ __forceinline__ unsigned short f2bf(float f) {
    union { float f; unsigned int u; } v; v.f = f;
    unsigned int r = (v.u + 0x7FFF + ((v.u >> 16) & 1)) >> 16;
    return (unsigned short)r;
}
__device__ __forceinline__ float bf2f(unsigned int hbits) {
    union { unsigned int u; float f; } v; v.u = hbits << 16;
    return v.f;
}

// ---------------- setup: zero counts | pack [W|W_res] to B-frag order | rel_logit ----------------
__global__ __launch_bounds__(256) void setup_kernel(
    int* __restrict__ counts, int N,
    const float* __restrict__ W, const float* __restrict__ W_res,
    unsigned short* __restrict__ WbPack,
    const float* __restrict__ W_r, const float* __restrict__ a,
    const float* __restrict__ rel_emb, float* __restrict__ rl,
    int n_rel, int rel_dim, int zb)
{
    __shared__ float a3[128];
    __shared__ float wa[128];
    int bid = blockIdx.x;
    int tid = threadIdx.x;
    if (bid < zb) {
        int i = bid * 256 + tid;
        if (i < N) counts[i] = 0;
        return;
    }
    if (bid < zb + 16) {
        int g = (bid - zb) * 256 + tid;   // 0..4095
        int t = g >> 8;
        int s = (g >> 6) & 3;
        int lane = g & 63;
        int ncol = ((t & 7) << 4) + (lane & 15);
        int k0 = s * 32 + ((lane >> 4) << 3);
        const float* srcw = (t < 8) ? W : W_res;
        unsigned short* dst = WbPack + ((size_t)(t * 4 + s) * 64 + lane) * 8;
        #pragma unroll
        for (int j = 0; j < 8; ++j) dst[j] = f2bf(srcw[(size_t)(k0 + j) * 128 + ncol]);
        return;
    }
    // rel_logit block
    if (tid < 128) {
        a3[tid] = a[256 + tid];
    }
    __syncthreads();
    if (tid < rel_dim) {
        float s = 0.f;
        for (int d = 0; d < 128; ++d) s += W_r[tid * 128 + d] * a3[d];
        wa[tid] = s;
    }
    __syncthreads();
    if (tid < n_rel) {
        float s = 0.f;
        for (int k = 0; k < rel_dim; ++k) s += rel_emb[tid * rel_dim + k] * wa[k];
        rl[tid] = s;
    }
}

// ---------------- dual GEMM via MFMA: [hb | resb] = bf16( X @ [W | W_res] ) + fused p/q ----------------
__global__ __launch_bounds__(256) void gemm_dual_kernel(
    const float* __restrict__ X, const unsigned short* __restrict__ WbPack,
    const float* __restrict__ b_res, const float* __restrict__ a,
    unsigned short* __restrict__ hb, unsigned short* __restrict__ resb,
    float* __restrict__ p, float* __restrict__ q, int M)
{
    __shared__ __align__(16) unsigned char smem[64 * LDS_STRIDE];
    __shared__ float pq_s[128];
    const int tid = threadIdx.x;
    const int lane = tid & 63;
    const int wave = tid >> 6;
    const int rowbase = blockIdx.x * 64;
    const int c16 = lane & 15;
    const int kq = lane >> 4;    // 0..3

    if (tid < 128) pq_s[tid] = 0.f;

    // hoist this wave's 16 W fragments (t = wave*4+tt, s = 0..3)
    bf16x8 wfrag[4][4];
    #pragma unroll
    for (int tt = 0; tt < 4; ++tt)
        #pragma unroll
        for (int s = 0; s < 4; ++s)
            wfrag[tt][s] = *(const bf16x8*)(WbPack + ((size_t)((wave * 4 + tt) * 4 + s) * 64 + lane) * 8);

    float bres[4];
    #pragma unroll
    for (int tt = 0; tt < 4; ++tt) {
        int t = wave * 4 + tt;
        bres[tt] = (t >= 8) ? b_res[(t - 8) * 16 + c16] : 0.f;
    }
    float pa[4], qa[4];
    #pragma unroll
    for (int tt = 0; tt < 4; ++tt) {
        int col = (wave * 4 + tt) * 16 + c16;
        pa[tt] = (wave < 2) ? a[col] : 0.f;
        qa[tt] = (wave < 2) ? a[128 + col] : 0.f;
    }

    // stage X tile (64 rows x 128 f32) -> LDS bf16
    #pragma unroll
    for (int j = 0; j < 8; ++j) {
        int ch = j * 256 + tid;            // 16B chunk id, 0..2047
        int r = ch >> 5;
        int c = ch & 31;
        int gr = rowbase + r; if (gr >= M) gr = M - 1;
        float4 v = *(const float4*)(X + (size_t)gr * 128 + c * 4);
        unsigned int u0 = ((unsigned)f2bf(v.y) << 16) | f2bf(v.x);
        unsigned int u1 = ((unsigned)f2bf(v.w) << 16) | f2bf(v.z);
        *(uint2*)(smem + r * LDS_STRIDE + c * 8) = make_uint2(u0, u1);
    }
    __syncthreads();

    f32x4 acc[4][4];
    #pragma unroll
    for (int rt = 0; rt < 4; ++rt)
        #pragma unroll
        for (int tt = 0; tt < 4; ++tt) acc[rt][tt] = (f32x4){0.f, 0.f, 0.f, 0.f};

    #pragma unroll
    for (int s = 0; s < 4; ++s) {
        #pragma unroll
        for (int rt = 0; rt < 4; ++rt) {
            int row = rt * 16 + c16;
            bf16x8 af = *(const bf16x8*)(smem + row * LDS_STRIDE + s * 64 + kq * 16);
            #pragma unroll
            for (int tt = 0; tt < 4; ++tt)
                acc[rt][tt] = __builtin_amdgcn_mfma_f32_16x16x32_bf16(af, wfrag[tt][s], acc[rt][tt], 0, 0, 0);
        }
    }
    __syncthreads();

    if (wave < 2) {
        #pragma unroll
        for (int rt = 0; rt < 4; ++rt) {
            #pragma unroll
            for (int i = 0; i < 4; ++i) {
                float pp = 0.f, qq = 0.f;
                #pragma unroll
                for (int tt = 0; tt < 4; ++tt) {
                    pp += acc[rt][tt][i] * pa[tt];
                    qq += acc[rt][tt][i] * qa[tt];
                }
                #pragma unroll
                for (int d = 1; d < 16; d <<= 1) {
                    pp += __shfl_xor(pp, d, 64);
                    qq += __shfl_xor(qq, d, 64);
                }
                if (c16 == 0) {
                    int r = rt * 16 + kq * 4 + i;
                    atomicAdd(&pq_s[r], pp);
                    atomicAdd(&pq_s[64 + r], qq);
                }
            }
        }
    }

    #pragma unroll
    for (int rt = 0; rt < 4; ++rt) {
        #pragma unroll
        for (int tt = 0; tt < 4; ++tt) {
            int colall = (wave * 4 + tt) * 16 + c16;
            #pragma unroll
            for (int i = 0; i < 4; ++i) {
                int row = rt * 16 + kq * 4 + i;
                *(unsigned short*)(smem + row * LDS_STRIDE + colall * 2) = f2bf(acc[rt][tt][i] + bres[tt]);
            }
        }
    }
    __syncthreads();

    #pragma unroll
    for (int j = 0; j < 4; ++j) {
        int ch = j * 256 + tid;
        int r = ch >> 4;
        int c = ch & 15;
        int gr = rowbase + r;
        uint4 hv = *(const uint4*)(smem + r * LDS_STRIDE + c * 16);
        uint4 rv = *(const uint4*)(smem + r * LDS_STRIDE + 256 + c * 16);
        if (gr < M) {
            *(uint4*)(hb + (size_t)gr * 128 + c * 8) = hv;
            *(uint4*)(resb + (size_t)gr * 128 + c * 8) = rv;
        }
    }
    if (tid < 64) {
        int gr = rowbase + tid;
        if (gr < M) { p[gr] = pq_s[tid]; q[gr] = pq_s[64 + tid]; }
    }
}

// ---------------- hist: rank within destination ----------------
__global__ __launch_bounds__(256) void hist_kernel(
    const int* __restrict__ dst, int* __restrict__ counts, int* __restrict__ rank, int E)
{
    int e = blockIdx.x * 256 + threadIdx.x;
    if (e < E) rank[e] = atomicAdd(&counts[dst[e]], 1);
}

__global__ __launch_bounds__(1024) void scan_block(const int* __restrict__ counts, int* __restrict__ tmp,
                                                   int* __restrict__ bsums, int n)
{
    __shared__ int wsum[16];
    int tid = threadIdx.x;
    int i = blockIdx.x * 1024 + tid;
    int v = (i < n) ? counts[i] : 0;
    int lane = tid & 63, w = tid >> 6;
    int x = v;
    #pragma unroll
    for (int d = 1; d < 64; d <<= 1) { int t = __shfl_up(x, d, 64); if (lane >= d) x += t; }
    if (lane == 63) wsum[w] = x;
    __syncthreads();
    if (w == 0) {
        int s = (lane < 16) ? wsum[lane] : 0;
        #pragma unroll
        for (int d = 1; d < 16; d <<= 1) { int t = __shfl_up(s, d, 64); if (lane >= d) s += t; }
        if (lane < 16) wsum[lane] = s;
    }
    __syncthreads();
    if (w > 0) x += wsum[w - 1];
    if (i < n) tmp[i] = x;
    if (tid == 1023) bsums[blockIdx.x] = x;
}

// finalize with in-block partial-scan of bsums (nb <= 64)
__global__ __launch_bounds__(1024) void finalize_offsets(
    const int* __restrict__ tmp, const int* __restrict__ counts,
    const int* __restrict__ bsums, int* __restrict__ offsets, int N, int E, int nb)
{
    __shared__ int bpref_s;
    int tid = threadIdx.x;
    if (tid < 64) {
        int v = (tid < nb && tid < (int)blockIdx.x) ? bsums[tid] : 0;
        v = waveSumI(v);
        if (tid == 0) bpref_s = v;
    }
    __syncthreads();
    int i = blockIdx.x * 1024 + tid;
    if (i < N) offsets[i] = tmp[i] - counts[i] + bpref_s;
    if (i == 0) offsets[N] = E;
}

// ---------------- fused logit+exp+scatter: pairs[offsets[d]+rank[e]] = (src, exp(logit)) ----------------
__global__ __launch_bounds__(256) void scatter_kernel(
    const int* __restrict__ src, const int* __restrict__ dst, const int* __restrict__ etype,
    const int* __restrict__ rank, const int* __restrict__ offsets,
    const float* __restrict__ p, const float* __restrict__ q, const float* __restrict__ rl,
    uint2* __restrict__ pairs, int E, int n_rel)
{
    __shared__ float rls[64];
    if (threadIdx.x < n_rel) rls[threadIdx.x] = rl[threadIdx.x];
    __syncthreads();
    int e = blockIdx.x * 256 + threadIdx.x;
    if (e >= E) return;
    int s = src[e], d = dst[e], t = etype[e];
    float l = p[d] + q[s] + rls[t];
    l = (l > 0.f) ? l : 0.2f * l;
    uint2 pk;
    pk.x = (unsigned int)s;
    pk.y = __float_as_uint(__expf(l));   // softmax shift-invariant; logits O(+-10), no overflow
    pairs[offsets[d] + rank[e]] = pk;
}

// ---------------- per-node normalize + aggregate + residual + SELU (1 wave / node) ----------------
__global__ __launch_bounds__(256) void agg_kernel(
    const unsigned short* __restrict__ hb, const unsigned short* __restrict__ resb,
    const int* __restrict__ offsets, const uint2* __restrict__ pairs,
    float* __restrict__ out, int N)
{
    int node = blockIdx.x * 4 + (threadIdx.x >> 6);
    int lane = threadIdx.x & 63;
    if (node >= N) return;
    int beg = offsets[node], end = offsets[node + 1];

    float a0 = 0.f, a1 = 0.f;
    float ssum = 0.f;
    const unsigned short* hlane = hb + lane * 2;
    for (int c = beg; c < end; c += 64) {
        int nn = min(64, end - c);
        uint2 pk = (lane < nn) ? pairs[c + lane] : make_uint2(0u, 0u);
        int   sv = (int)pk.x;
        float se = __uint_as_float(pk.y);
        ssum += se;
        int j = 0;
        for (; j + 7 < nn; j += 8) {
            float w[8]; int r[8]; unsigned int v[8];
            #pragma unroll
            for (int u = 0; u < 8; ++u) { w[u] = __shfl(se, j + u); r[u] = __shfl(sv, j + u); }
            #pragma unroll
            for (int u = 0; u < 8; ++u) v[u] = *(const unsigned int*)(hlane + (size_t)r[u] * 128);
            #pragma unroll
            for (int u = 0; u < 8; ++u) {
                a0 += w[u] * bf2f(v[u] & 0xffff);
                a1 += w[u] * bf2f(v[u] >> 16);
            }
        }
        for (; j + 3 < nn; j += 4) {
            float w[4]; int r[4]; unsigned int v[4];
            #pragma unroll
            for (int u = 0; u < 4; ++u) { w[u] = __shfl(se, j + u); r[u] = __shfl(sv, j + u); }
            #pragma unroll
            for (int u = 0; u < 4; ++u) v[u] = *(const unsigned int*)(hlane + (size_t)r[u] * 128);
            #pragma unroll
            for (int u = 0; u < 4; ++u) {
                a0 += w[u] * bf2f(v[u] & 0xffff);
                a1 += w[u] * bf2f(v[u] >> 16);
            }
        }
        for (; j < nn; ++j) {
            float w = __shfl(se, j);
            int r = __shfl(sv, j);
            unsigned int v = *(const unsigned int*)(hlane + (size_t)r * 128);
            a0 += w * bf2f(v & 0xffff);
            a1 += w * bf2f(v >> 16);
        }
    }
    ssum = waveSum(ssum);
    float inv = 1.0f / (ssum + 1e-16f);
    a0 *= inv; a1 *= inv;

    unsigned int rv = *(const unsigned int*)(resb + (size_t)node * 128 + lane * 2);
    float o0 = a0 + bf2f(rv & 0xffff), o1 = a1 + bf2f(rv >> 16);
    const float SC = 1.0507009873554805f, AL = 1.6732632423543772f;
    o0 = (o0 > 0.f) ? SC * o0 : SC * AL * (__expf(o0) - 1.f);
    o1 = (o1 > 0.f) ? SC * o1 : SC * AL * (__expf(o1) - 1.f);
    *(float2*)(out + (size_t)node * 128 + lane * 2) = make_float2(o0, o1);
}

// ---------------- launch ----------------
extern "C" void kernel_launch(void* const* d_in, const int* in_sizes, int n_in,
                              void* d_out, int out_size, void* d_ws, size_t ws_size,
                              hipStream_t stream)
{
    const float* X      = (const float*)d_in[0];
    const int*   ei     = (const int*)d_in[1];
    const int*   etype  = (const int*)d_in[2];
    const float* W      = (const float*)d_in[3];
    const float* W_r    = (const float*)d_in[4];
    const float* a      = (const float*)d_in[5];
    const float* W_res  = (const float*)d_in[6];
    const float* b_res  = (const float*)d_in[7];
    const float* rel_emb= (const float*)d_in[8];

    const int N = in_sizes[0] / 128;     // 50000
    const int E = in_sizes[2];           // 600000
    const int n_rel = in_sizes[8] / 100; // 40
    const int* src = ei;
    const int* dst = ei + E;

    // workspace carve (256B aligned)
    char* w = (char*)d_ws;
    auto alloc = [&](size_t bytes) -> void* {
        void* ptr = (void*)w;
        w += (bytes + 255) & ~(size_t)255;
        return ptr;
    };
    unsigned short* WbPack = (unsigned short*)alloc((size_t)16 * 4 * 64 * 8 * 2);
    unsigned short* hb     = (unsigned short*)alloc((size_t)N * 128 * 2);
    unsigned short* resb   = (unsigned short*)alloc((size_t)N * 128 * 2);
    float* p       = (float*)alloc((size_t)N * 4);
    float* q       = (float*)alloc((size_t)N * 4);
    float* rl      = (float*)alloc(64 * 4);
    int*   counts  = (int*)alloc((size_t)N * 4);
    int*   tmp     = (int*)alloc((size_t)(N + 2) * 4);
    int*   offsets = (int*)alloc((size_t)(N + 2) * 4);
    int*   bsums   = (int*)alloc(256 * 4);
    int*   rank    = (int*)alloc((size_t)E * 4);
    uint2* pairs   = (uint2*)alloc((size_t)E * 8);
    float* out     = (float*)d_out;

    const int zb = (N + 255) / 256;                 // 196
    const int gemm_blocks = (N + 63) / 64;          // 782
    const int node_wave_blocks = (N + 3) / 4;       // 12500
    const int edge_blocks = (E + 255) / 256;        // 2344
    const int scan_blocks = (N + 1023) / 1024;      // 49

    setup_kernel<<<zb + 17, 256, 0, stream>>>(counts, N, W, W_res, WbPack,
                                              W_r, a, rel_emb, rl, n_rel, 100, zb);
    hist_kernel<<<edge_blocks, 256, 0, stream>>>(dst, counts, rank, E);
    scan_block<<<scan_blocks, 1024, 0, stream>>>(counts, tmp, bsums, N);
    finalize_offsets<<<scan_blocks, 1024, 0, stream>>>(tmp, counts, bsums, offsets, N, E, scan_blocks);
    gemm_dual_kernel<<<gemm_blocks, 256, 0, stream>>>(X, WbPack, b_res, a, hb, resb, p, q, N);
    scatter_kernel<<<edge_blocks, 256, 0, stream>>>(src, dst, etype, rank, offsets,
                                                    p, q, rl, pairs, E, n_rel);
    agg_kernel<<<node_wave_blocks, 256, 0, stream>>>(hb, resb, offsets, pairs, out, N);
}